// Round 8
// baseline (575.299 us; speedup 1.0000x reference)
//
#include <hip/hip_runtime.h>

#define Bn 65536
#define Tn 100
#define Cn 7

typedef short short8 __attribute__((ext_vector_type(8)));   // 8 bf16 = 4 VGPRs (MFMA A/B frag)
typedef float float4v __attribute__((ext_vector_type(4)));  // MFMA C/D frag
typedef float float2v __attribute__((ext_vector_type(2)));  // v_pk_* packed fp32

__device__ __forceinline__ float2v pk_fma(float2v a, float2v b, float2v c) {
    return __builtin_elementwise_fma(a, b, c);
}
__device__ __forceinline__ float2v pk2(float v) { return (float2v){v, v}; }

__device__ __forceinline__ float fast_rcp(float x) { return __builtin_amdgcn_rcpf(x); }
__device__ __forceinline__ float sig_f(float x) { return fast_rcp(1.f + __expf(-x)); }
__device__ __forceinline__ float tanh_f(float x) { return 1.f - 2.f * fast_rcp(__expf(2.f * x) + 1.f); }
// round-to-nearest-even fp32 -> bf16 (finite values only)
__device__ __forceinline__ unsigned bf16rne(float x) {
    unsigned u = __float_as_uint(x);
    return (u + 0x7fffu + ((u >> 16) & 1u)) >> 16;
}
__device__ __forceinline__ float bf_lo(unsigned u) { return __uint_as_float(u << 16); }
__device__ __forceinline__ float bf_hi(unsigned u) { return __uint_as_float(u & 0xffff0000u); }

// lane^1 exchange via DPP quad_perm [1,0,3,2] — stays in the VALU pipe (no LDS)
__device__ __forceinline__ float dpp_xor1(float x) {
    return __uint_as_float((unsigned)__builtin_amdgcn_mov_dpp(
        (int)__float_as_uint(x), 0xB1, 0xF, 0xF, true));
}

typedef const __attribute__((address_space(1))) void* gp_t;
typedef __attribute__((address_space(3))) void* sp_t;
__device__ __forceinline__ void async_copy_dw(const void* g, void* l) {
    __builtin_amdgcn_global_load_lds((gp_t)g, (sp_t)l, 4, 0, 0);
}

// ---------------- K0: gather fc1_w into per-(window,dir) bf16 B-panels ----------------
__global__ void w2prep_kernel(const float* __restrict__ fc1_w, unsigned short* __restrict__ w2g) {
    int idx = blockIdx.x * 256 + threadIdx.x;   // 40960 total
    int w  = idx >> 12;
    int d  = (idx >> 11) & 1;
    int n  = (idx >> 5) & 63;
    int kk = idx & 31;
    int tt = kk >> 1, i = kk & 1;
    int t  = d ? (99 - 10 * w - tt) : (10 * w + tt);
    float v = (kk < 20) ? fc1_w[n * 400 + 4 * t + 2 * d + i] : 0.f;
    w2g[idx] = (unsigned short)bf16rne(v);
}

// ---------------- K1: bidirectional LSTM layer 0 ----------------
// R8: l0 was stall-bound (R7: halved FMAs, duration flat, VALUBusy 58->48).
// Fixes: (1) LDS panel [sample][28] -> 7x ds_read_b128 pulls the whole 4-step
// chunk into 28 VGPRs at chunk top (one lgkm wait/chunk, step loop is pure-reg);
// (2) chunk=4 -> LDS 28,672 B -> 5 blocks/CU = 20 waves/CU. Staging: exactly 14
// global_load_lds per wave per chunk (112 B runs); wait vmcnt(4) leaves the 4 h1
// stores in flight. Barrier-free per-wave structure + packed-fp32 gates kept.
__global__ __launch_bounds__(256, 5) void l0_kernel(
    const float* __restrict__ x,
    const float* __restrict__ wih_f, const float* __restrict__ whh_f,
    const float* __restrict__ bih_f, const float* __restrict__ bhh_f,
    const float* __restrict__ wih_r, const float* __restrict__ whh_r,
    const float* __restrict__ bih_r, const float* __restrict__ bhh_r,
    unsigned* __restrict__ h1u)
{
    __shared__ float xs[4][2][896];   // [wave][parity][32 samples * 28 floats] = 28,672 B

    const int tid  = threadIdx.x;
    const int wv   = tid >> 6;          // 0..3
    const int lane = tid & 63;
    const int rev  = wv >> 1;           // waves 0-1: fwd, 2-3: rev
    const int sgrp = wv & 1;            // sample group within block
    const int cid  = lane & 1;          // hidden channel
    const int s    = lane >> 1;         // sample within wave (0..31)
    const int b    = blockIdx.x * 64 + sgrp * 32 + s;

    const float* wih = rev ? wih_r : wih_f;
    const float* whh = rev ? whh_r : whh_f;
    const float* bih = rev ? bih_r : bih_f;
    const float* bhh = rev ? bhh_r : bhh_f;

    // packed gate pairs: p=0 -> (i,f), p=1 -> (g,o); rows k0=cid+4p, k1=cid+4p+2
    float2v wi2[2][7], whA2[2], whB2[2], bias2[2];
#pragma unroll
    for (int p = 0; p < 2; ++p) {
        const int k0 = cid + 4 * p, k1 = cid + 4 * p + 2;
#pragma unroll
        for (int c = 0; c < 7; ++c)
            wi2[p][c] = (float2v){wih[k0 * 7 + c], wih[k1 * 7 + c]};
        whA2[p]  = (float2v){whh[k0 * 2 + cid], whh[k1 * 2 + cid]};
        whB2[p]  = (float2v){whh[k0 * 2 + (cid ^ 1)], whh[k1 * 2 + (cid ^ 1)]};
        bias2[p] = (float2v){bih[k0] + bhh[k0], bih[k1] + bhh[k1]};
    }

    // per-wave private staging: 32 samples x 28 floats = 896 elems = exactly 14 loads.
    // e = i*64+lane -> sample=e/28, r=e%28; +64 => s+=2, r+=8; r>=28 -> s+=1, r-=28.
    const int s0 = lane / 28;           // 0..2
    const int r0 = lane - 28 * s0;
    const float* xsamp = x + (size_t)(blockIdx.x * 64 + sgrp * 32 + s0) * 700;

    auto stage = [&](int ch, int p) {
        const int off = rev ? (672 - 28 * ch) : (28 * ch);
        const float* g = xsamp + off + r0;
        float* l = &xs[wv][p][lane];
        int r = r0;
#pragma unroll
        for (int i = 0; i < 14; ++i) {
            async_copy_dw(g, l);
            l += 64;
            const int c = (r >= 20) ? 1 : 0;    // r+8 >= 28 -> extra sample carry
            g += c ? 2080 : 1408;               // 3*700+8-28 : 2*700+8
            r += c ? -20 : 8;
        }
    };

    float hs = 0.f, ho = 0.f, cc = 0.f;

    stage(0, 0);
#pragma unroll 1
    for (int chk = 0; chk < 25; ++chk) {
        // drain this wave's 14 chunk loads; leave the 4 newest (h1 stores) in flight
        if (chk == 0) __builtin_amdgcn_s_waitcnt(0x0F70);
        else          __builtin_amdgcn_s_waitcnt(0x0F74);
        __builtin_amdgcn_sched_barrier(0);   // fence: no ds_read hoists above the wait
        if (chk < 24) stage(chk + 1, (chk + 1) & 1);
        __builtin_amdgcn_sched_barrier(0);   // keep stage loads older than compute

        // pull this lane's whole chunk (own sample's 28 floats) into registers
        const float* xp = &xs[wv][chk & 1][s * 28];
        float4v xv[7];
#pragma unroll
        for (int k = 0; k < 7; ++k) xv[k] = *(const float4v*)(xp + k * 4);
        const float* xf = (const float*)xv;   // xf[rr*7 + c]

        const int t0 = rev ? (99 - 4 * chk) : (4 * chk);
#pragma unroll
        for (int tt = 0; tt < 4; ++tt) {
            const int rr = rev ? (3 - tt) : tt;                 // row within chunk
            const int t  = rev ? (t0 - tt) : (t0 + tt);

            float2v g0 = bias2[0], g1 = bias2[1];
#pragma unroll
            for (int c = 0; c < 7; ++c) {
                const float xvv = xf[rr * 7 + c];
                g0 = pk_fma(wi2[0][c], pk2(xvv), g0);
                g1 = pk_fma(wi2[1][c], pk2(xvv), g1);
            }
            g0 = pk_fma(whA2[0], pk2(hs), pk_fma(whB2[0], pk2(ho), g0));
            g1 = pk_fma(whA2[1], pk2(hs), pk_fma(whB2[1], pk2(ho), g1));

            const float iv = sig_f(g0.x);
            const float fv = sig_f(g0.y);
            const float qv = tanh_f(g1.x);
            const float ov = sig_f(g1.y);
            cc = fmaf(fv, cc, iv * qv);
            hs = ov * tanh_f(cc);
            ho = dpp_xor1(hs);          // partner channel's h

            if (cid == 0)               // even lanes: pack (h0,h1), 1 store/step/wave
                h1u[((size_t)t * 2 + rev) * Bn + b] = bf16rne(hs) | (bf16rne(ho) << 16);
        }
    }
}

// ---------------- K2: LSTM layer 1 + MFMA-fc1 + fc2 ----------------
// (R6/R7 version, kept: barrier-free; wave-private hst slab + a2; B-frags from
// L2-hot w2g; per-dir partial acc summed in epilogue; packed-fp32 gates.)
__global__ __launch_bounds__(256, 4) void l1fc_kernel(
    const unsigned* __restrict__ hin,   // [T][2][B] packed bf16 pairs
    const float* __restrict__ wih_f, const float* __restrict__ whh_f,
    const float* __restrict__ bih_f, const float* __restrict__ bhh_f,
    const float* __restrict__ wih_r, const float* __restrict__ whh_r,
    const float* __restrict__ bih_r, const float* __restrict__ bhh_r,
    const unsigned* __restrict__ w2g,   // [10][2][64][32] bf16 = [10][2][64][16] dw
    const float* __restrict__ fc1_b,
    const float* __restrict__ fc2_w,    // [20][64]
    const float* __restrict__ fc2_b,
    float* __restrict__ out)            // [B][20]
{
    __shared__ unsigned smem[7680];     // 30,720 B: a2 [4][32][20] + hst [4][2][2][10][32]

    const int tid  = threadIdx.x;
    const int wv   = tid >> 6;          // 0..3
    const int lane = tid & 63;
    const int d    = wv >> 1;           // waves 0-1: fwd, 2-3: rev
    const int shalf = wv & 1;
    const int cid  = lane & 1;
    const int sp   = lane >> 1;         // 0..31 sample-in-wave
    const int b0   = blockIdx.x * 64;

    unsigned* a2w  = smem + wv * 640;           // per-wave [32][20] dw (cols 10..15 K-pad)
    unsigned* hstw = smem + 2560 + wv * 1280;   // per-wave [2buf][2p][10][32] dw

    const float* wih = d ? wih_r : wih_f;
    const float* whh = d ? whh_r : whh_f;
    const float* bih = d ? bih_r : bih_f;
    const float* bhh = d ? bhh_r : bhh_f;

    float2v wi2[2][4], whA2[2], whB2[2], bias2[2];
#pragma unroll
    for (int p = 0; p < 2; ++p) {
        const int k0 = cid + 4 * p, k1 = cid + 4 * p + 2;
#pragma unroll
        for (int m = 0; m < 4; ++m)
            wi2[p][m] = (float2v){wih[k0 * 4 + m], wih[k1 * 4 + m]};
        whA2[p]  = (float2v){whh[k0 * 2 + cid], whh[k1 * 2 + cid]};
        whB2[p]  = (float2v){whh[k0 * 2 + (cid ^ 1)], whh[k1 * 2 + (cid ^ 1)]};
        bias2[p] = (float2v){bih[k0] + bhh[k0], bih[k1] + bhh[k1]};
    }

    float4v acc[2][4];                  // [mt][nt] partial C for this wave's dir
#pragma unroll
    for (int mt = 0; mt < 2; ++mt)
#pragma unroll
        for (int nt = 0; nt < 4; ++nt) acc[mt][nt] = (float4v){0.f, 0.f, 0.f, 0.f};

    for (int i = lane; i < 640; i += 64) a2w[i] = 0u;   // zero incl. K-pad cols (wave-private)

    // wave-private h slab: 20 rows R=[p][j] of 32 dw; LDS dst = uniform base + lane
    auto stage_h = [&](int w, int pb) {
        unsigned* dst = hstw + pb * 640;
        const int col = lane & 31;
        const int Rb  = lane >> 5;         // 0/1
#pragma unroll
        for (int i = 0; i < 10; ++i) {
            const int R = Rb + 2 * i;      // 0..19
            const int p = (R >= 10) ? 1 : 0;
            const int j = R - 10 * p;
            const int t = d ? (99 - (10 * w + j)) : (10 * w + j);
            async_copy_dw(hin + ((size_t)t * 2 + p) * Bn + b0 + shalf * 32 + col,
                          dst + R * 32 + col);
        }
    };

    stage_h(0, 0);

    float hs = 0.f, ho = 0.f, cc = 0.f;
    const int q = lane >> 4, l16 = lane & 15;

#pragma unroll 1
    for (int w = 0; w < 10; ++w) {
        __builtin_amdgcn_s_waitcnt(0x0F70);   // this window's h slab landed
        __builtin_amdgcn_sched_barrier(0);

        // B-fragments for this window/dir straight from global (L2/L3-hot, 1KB/wave)
        short8 bv[4];
#pragma unroll
        for (int nt = 0; nt < 4; ++nt)
            bv[nt] = *(const short8*)&w2g[w * 2048 + d * 1024 + (nt * 16 + l16) * 16 + q * 4];

        if (w < 9) stage_h(w + 1, (w + 1) & 1);
        __builtin_amdgcn_sched_barrier(0);

        // ---- 10 LSTM steps (wave-private LDS only) ----
        const unsigned* hb = hstw + (w & 1) * 640;
#pragma unroll 2
        for (int j = 0; j < 10; ++j) {
            const unsigned uF = hb[j * 32 + sp];
            const unsigned uR = hb[320 + j * 32 + sp];
            const float a0 = bf_lo(uF), a1 = bf_hi(uF);
            const float a2v = bf_lo(uR), a3 = bf_hi(uR);

            float2v g0 = bias2[0], g1 = bias2[1];
            g0 = pk_fma(wi2[0][0], pk2(a0), g0);  g1 = pk_fma(wi2[1][0], pk2(a0), g1);
            g0 = pk_fma(wi2[0][1], pk2(a1), g0);  g1 = pk_fma(wi2[1][1], pk2(a1), g1);
            g0 = pk_fma(wi2[0][2], pk2(a2v), g0); g1 = pk_fma(wi2[1][2], pk2(a2v), g1);
            g0 = pk_fma(wi2[0][3], pk2(a3), g0);  g1 = pk_fma(wi2[1][3], pk2(a3), g1);
            g0 = pk_fma(whA2[0], pk2(hs), pk_fma(whB2[0], pk2(ho), g0));
            g1 = pk_fma(whA2[1], pk2(hs), pk_fma(whB2[1], pk2(ho), g1));

            const float iv = sig_f(g0.x);
            const float fv = sig_f(g0.y);
            const float qv = tanh_f(g1.x);
            const float ov = sig_f(g1.y);
            cc = fmaf(fv, cc, iv * qv);
            hs = ov * tanh_f(cc);
            ho = dpp_xor1(hs);

            if (cid == 0)
                a2w[sp * 20 + j] = bf16rne(fmaxf(hs, 0.f)) | (bf16rne(fmaxf(ho, 0.f)) << 16);
        }
        asm volatile("s_waitcnt lgkmcnt(0)");   // a2 writes visible to own wave's lanes
        __builtin_amdgcn_sched_barrier(0);

        // ---- MFMA: partial C[32x64] (this dir) += A2·W2^T, K=32; 2 m-tiles x 4 n-tiles
        {
            short8 av0 = *(const short8*)&a2w[l16 * 20 + q * 4];
            short8 av1 = *(const short8*)&a2w[(16 + l16) * 20 + q * 4];
#pragma unroll
            for (int nt = 0; nt < 4; ++nt) {
                acc[0][nt] = __builtin_amdgcn_mfma_f32_16x16x32_bf16(av0, bv[nt], acc[0][nt], 0, 0, 0);
                acc[1][nt] = __builtin_amdgcn_mfma_f32_16x16x32_bf16(av1, bv[nt], acc[1][nt], 0, 0, 0);
            }
        }
    }

    // ---- epilogue: sum dir partials in LDS, +bias, relu, fc2, out ----
    __syncthreads();                       // all waves done with hst/a2; safe to reuse smem
    float* eb = (float*)smem;              // [64][65]
    if (d == 0) {
#pragma unroll
        for (int mt = 0; mt < 2; ++mt)
#pragma unroll
            for (int nt = 0; nt < 4; ++nt)
#pragma unroll
                for (int r = 0; r < 4; ++r)
                    eb[(shalf * 32 + mt * 16 + q * 4 + r) * 65 + nt * 16 + l16] = acc[mt][nt][r];
    }
    __syncthreads();
    if (d == 1) {
#pragma unroll
        for (int mt = 0; mt < 2; ++mt)
#pragma unroll
            for (int nt = 0; nt < 4; ++nt)
#pragma unroll
                for (int r = 0; r < 4; ++r)
                    eb[(shalf * 32 + mt * 16 + q * 4 + r) * 65 + nt * 16 + l16] += acc[mt][nt][r];
    }
    __syncthreads();

    const float* ebr = (const float*)smem;
    const int sm2 = tid & 63;
    const int og  = (tid >> 6) * 5;        // 4 groups x 5 outputs
    float z[64];
#pragma unroll
    for (int k = 0; k < 64; ++k) z[k] = fmaxf(ebr[sm2 * 65 + k] + fc1_b[k], 0.f);
    float y[5];
#pragma unroll
    for (int o = 0; o < 5; ++o) {
        float r2 = fc2_b[og + o];
#pragma unroll
        for (int k = 0; k < 64; ++k) r2 = fmaf(fc2_w[(og + o) * 64 + k], z[k], r2);
        y[o] = r2;
    }
    __syncthreads();
    float* ebw = (float*)smem;
#pragma unroll
    for (int o = 0; o < 5; ++o) ebw[sm2 * 20 + og + o] = y[o];
    __syncthreads();
    for (int f = tid; f < 1280; f += 256)
        out[(size_t)blockIdx.x * 1280 + f] = ebw[f];
}

extern "C" void kernel_launch(void* const* d_in, const int* in_sizes, int n_in,
                              void* d_out, int out_size, void* d_ws, size_t ws_size,
                              hipStream_t stream) {
    const float* x = (const float*)d_in[0];
    const float* w_ih_l0  = (const float*)d_in[1];
    const float* w_hh_l0  = (const float*)d_in[2];
    const float* b_ih_l0  = (const float*)d_in[3];
    const float* b_hh_l0  = (const float*)d_in[4];
    const float* w_ih_l0r = (const float*)d_in[5];
    const float* w_hh_l0r = (const float*)d_in[6];
    const float* b_ih_l0r = (const float*)d_in[7];
    const float* b_hh_l0r = (const float*)d_in[8];
    const float* w_ih_l1  = (const float*)d_in[9];
    const float* w_hh_l1  = (const float*)d_in[10];
    const float* b_ih_l1  = (const float*)d_in[11];
    const float* b_hh_l1  = (const float*)d_in[12];
    const float* w_ih_l1r = (const float*)d_in[13];
    const float* w_hh_l1r = (const float*)d_in[14];
    const float* b_ih_l1r = (const float*)d_in[15];
    const float* b_hh_l1r = (const float*)d_in[16];
    const float* fc1_w = (const float*)d_in[17];
    const float* fc1_b = (const float*)d_in[18];
    const float* fc2_w = (const float*)d_in[19];
    const float* fc2_b = (const float*)d_in[20];

    unsigned* h1u = (unsigned*)d_ws;                                // [100][2][65536] u32 = 52,428,800 B
    unsigned short* w2g = (unsigned short*)((char*)d_ws + (size_t)Tn * 2 * Bn * 4);  // 81,920 B

    w2prep_kernel<<<160, 256, 0, stream>>>(fc1_w, w2g);
    l0_kernel<<<1024, 256, 0, stream>>>(x,
        w_ih_l0, w_hh_l0, b_ih_l0, b_hh_l0,
        w_ih_l0r, w_hh_l0r, b_ih_l0r, b_hh_l0r, h1u);
    l1fc_kernel<<<1024, 256, 0, stream>>>(h1u,
        w_ih_l1, w_hh_l1, b_ih_l1, b_hh_l1,
        w_ih_l1r, w_hh_l1r, b_ih_l1r, b_hh_l1r,
        (const unsigned*)w2g, fc1_b, fc2_w, fc2_b, (float*)d_out);
}

// Round 9
// 402.727 us; speedup vs baseline: 1.4285x; 1.4285x over previous
//
#include <hip/hip_runtime.h>

#define Bn 65536
#define Tn 100
#define Cn 7

typedef short short8 __attribute__((ext_vector_type(8)));   // 8 bf16 = 4 VGPRs (MFMA A/B frag)
typedef float float4v __attribute__((ext_vector_type(4)));  // MFMA C/D frag
typedef float float2v __attribute__((ext_vector_type(2)));  // v_pk_* packed fp32

__device__ __forceinline__ float2v pk_fma(float2v a, float2v b, float2v c) {
    return __builtin_elementwise_fma(a, b, c);
}
__device__ __forceinline__ float2v pk2(float v) { return (float2v){v, v}; }

__device__ __forceinline__ float fast_rcp(float x) { return __builtin_amdgcn_rcpf(x); }
__device__ __forceinline__ float sig_f(float x) { return fast_rcp(1.f + __expf(-x)); }
__device__ __forceinline__ float tanh_f(float x) { return 1.f - 2.f * fast_rcp(__expf(2.f * x) + 1.f); }
// round-to-nearest-even fp32 -> bf16 (finite values only)
__device__ __forceinline__ unsigned bf16rne(float x) {
    unsigned u = __float_as_uint(x);
    return (u + 0x7fffu + ((u >> 16) & 1u)) >> 16;
}
__device__ __forceinline__ float bf_lo(unsigned u) { return __uint_as_float(u << 16); }
__device__ __forceinline__ float bf_hi(unsigned u) { return __uint_as_float(u & 0xffff0000u); }

// lane^1 exchange via DPP quad_perm [1,0,3,2] — stays in the VALU pipe (no LDS)
__device__ __forceinline__ float dpp_xor1(float x) {
    return __uint_as_float((unsigned)__builtin_amdgcn_mov_dpp(
        (int)__float_as_uint(x), 0xB1, 0xF, 0xF, true));
}

typedef const __attribute__((address_space(1))) void* gp_t;
typedef __attribute__((address_space(3))) void* sp_t;
__device__ __forceinline__ void async_copy_dw(const void* g, void* l) {
    __builtin_amdgcn_global_load_lds((gp_t)g, (sp_t)l, 4, 0, 0);
}

// ---------------- K0: gather fc1_w into per-(window,dir) bf16 B-panels ----------------
__global__ void w2prep_kernel(const float* __restrict__ fc1_w, unsigned short* __restrict__ w2g) {
    int idx = blockIdx.x * 256 + threadIdx.x;   // 40960 total
    int w  = idx >> 12;
    int d  = (idx >> 11) & 1;
    int n  = (idx >> 5) & 63;
    int kk = idx & 31;
    int tt = kk >> 1, i = kk & 1;
    int t  = d ? (99 - 10 * w - tt) : (10 * w + tt);
    float v = (kk < 20) ? fc1_w[n * 400 + 4 * t + 2 * d + i] : 0.f;
    w2g[idx] = (unsigned short)bf16rne(v);
}

// ---------------- K1: bidirectional LSTM layer 0 ----------------
// R9: R8's structure with the rule-#20 scratch spill fixed. R8's xf[rr*7+c] had
// runtime rr (rev-dependent) -> xv[7] went to scratch: WRITE_SIZE 51->359 MB.
// Fix: rev is WAVE-UNIFORM -> uniform if(rev)/else arms; row index is a macro
// LITERAL in each expansion -> all xv indices compile-time -> registers.
// launch_bounds(256,4): VGPR cap 128 (no forced spill); LDS 28,672 B still
// allows 5 blocks/CU opportunistically if allocation <= 102 VGPR.
#define XFE(i) (xv[(i) >> 2][(i) & 3])
#define L0_STEP(RR, TV) do {                                                          \
    float2v g0 = bias2[0], g1 = bias2[1];                                             \
    g0 = pk_fma(wi2[0][0], pk2(XFE((RR)*7+0)), g0);                                   \
    g1 = pk_fma(wi2[1][0], pk2(XFE((RR)*7+0)), g1);                                   \
    g0 = pk_fma(wi2[0][1], pk2(XFE((RR)*7+1)), g0);                                   \
    g1 = pk_fma(wi2[1][1], pk2(XFE((RR)*7+1)), g1);                                   \
    g0 = pk_fma(wi2[0][2], pk2(XFE((RR)*7+2)), g0);                                   \
    g1 = pk_fma(wi2[1][2], pk2(XFE((RR)*7+2)), g1);                                   \
    g0 = pk_fma(wi2[0][3], pk2(XFE((RR)*7+3)), g0);                                   \
    g1 = pk_fma(wi2[1][3], pk2(XFE((RR)*7+3)), g1);                                   \
    g0 = pk_fma(wi2[0][4], pk2(XFE((RR)*7+4)), g0);                                   \
    g1 = pk_fma(wi2[1][4], pk2(XFE((RR)*7+4)), g1);                                   \
    g0 = pk_fma(wi2[0][5], pk2(XFE((RR)*7+5)), g0);                                   \
    g1 = pk_fma(wi2[1][5], pk2(XFE((RR)*7+5)), g1);                                   \
    g0 = pk_fma(wi2[0][6], pk2(XFE((RR)*7+6)), g0);                                   \
    g1 = pk_fma(wi2[1][6], pk2(XFE((RR)*7+6)), g1);                                   \
    g0 = pk_fma(whA2[0], pk2(hs), pk_fma(whB2[0], pk2(ho), g0));                      \
    g1 = pk_fma(whA2[1], pk2(hs), pk_fma(whB2[1], pk2(ho), g1));                      \
    const float iv = sig_f(g0.x);                                                     \
    const float fv = sig_f(g0.y);                                                     \
    const float qv = tanh_f(g1.x);                                                    \
    const float ov = sig_f(g1.y);                                                     \
    cc = fmaf(fv, cc, iv * qv);                                                       \
    hs = ov * tanh_f(cc);                                                             \
    ho = dpp_xor1(hs);                                                                \
    if (cid == 0)                                                                     \
        h1u[((size_t)(TV) * 2 + rev) * Bn + b] = bf16rne(hs) | (bf16rne(ho) << 16);   \
} while (0)

__global__ __launch_bounds__(256, 4) void l0_kernel(
    const float* __restrict__ x,
    const float* __restrict__ wih_f, const float* __restrict__ whh_f,
    const float* __restrict__ bih_f, const float* __restrict__ bhh_f,
    const float* __restrict__ wih_r, const float* __restrict__ whh_r,
    const float* __restrict__ bih_r, const float* __restrict__ bhh_r,
    unsigned* __restrict__ h1u)
{
    __shared__ float xs[4][2][896];   // [wave][parity][32 samples * 28 floats] = 28,672 B

    const int tid  = threadIdx.x;
    const int wv   = tid >> 6;          // 0..3
    const int lane = tid & 63;
    const int rev  = wv >> 1;           // waves 0-1: fwd, 2-3: rev
    const int sgrp = wv & 1;            // sample group within block
    const int cid  = lane & 1;          // hidden channel
    const int s    = lane >> 1;         // sample within wave (0..31)
    const int b    = blockIdx.x * 64 + sgrp * 32 + s;

    const float* wih = rev ? wih_r : wih_f;
    const float* whh = rev ? whh_r : whh_f;
    const float* bih = rev ? bih_r : bih_f;
    const float* bhh = rev ? bhh_r : bhh_f;

    // packed gate pairs: p=0 -> (i,f), p=1 -> (g,o); rows k0=cid+4p, k1=cid+4p+2
    float2v wi2[2][7], whA2[2], whB2[2], bias2[2];
#pragma unroll
    for (int p = 0; p < 2; ++p) {
        const int k0 = cid + 4 * p, k1 = cid + 4 * p + 2;
#pragma unroll
        for (int c = 0; c < 7; ++c)
            wi2[p][c] = (float2v){wih[k0 * 7 + c], wih[k1 * 7 + c]};
        whA2[p]  = (float2v){whh[k0 * 2 + cid], whh[k1 * 2 + cid]};
        whB2[p]  = (float2v){whh[k0 * 2 + (cid ^ 1)], whh[k1 * 2 + (cid ^ 1)]};
        bias2[p] = (float2v){bih[k0] + bhh[k0], bih[k1] + bhh[k1]};
    }

    // per-wave private staging: 32 samples x 28 floats = 896 elems = exactly 14 loads.
    const int s0 = lane / 28;           // 0..2
    const int r0 = lane - 28 * s0;
    const float* xsamp = x + (size_t)(blockIdx.x * 64 + sgrp * 32 + s0) * 700;

    auto stage = [&](int ch, int p) {
        const int off = rev ? (672 - 28 * ch) : (28 * ch);
        const float* g = xsamp + off + r0;
        float* l = &xs[wv][p][lane];
        int r = r0;
#pragma unroll
        for (int i = 0; i < 14; ++i) {
            async_copy_dw(g, l);
            l += 64;
            const int c = (r >= 20) ? 1 : 0;    // r+8 >= 28 -> extra sample carry
            g += c ? 2080 : 1408;               // 3*700+8-28 : 2*700+8
            r += c ? -20 : 8;
        }
    };

    float hs = 0.f, ho = 0.f, cc = 0.f;

    stage(0, 0);
#pragma unroll 1
    for (int chk = 0; chk < 25; ++chk) {
        // drain this wave's 14 chunk loads; leave the 4 newest (h1 stores) in flight
        if (chk == 0) __builtin_amdgcn_s_waitcnt(0x0F70);
        else          __builtin_amdgcn_s_waitcnt(0x0F74);
        __builtin_amdgcn_sched_barrier(0);   // fence: no ds_read hoists above the wait
        if (chk < 24) stage(chk + 1, (chk + 1) & 1);
        __builtin_amdgcn_sched_barrier(0);   // keep stage loads older than compute

        // pull this lane's whole chunk (own sample's 28 floats) into registers
        const float* xp = &xs[wv][chk & 1][s * 28];
        float4v xv[7];
#pragma unroll
        for (int k = 0; k < 7; ++k) xv[k] = *(const float4v*)(xp + k * 4);

        // rev is wave-uniform: each arm has literal row indices -> xv stays in VGPRs
        if (rev) {
            const int t0 = 99 - 4 * chk;
            L0_STEP(3, t0);
            L0_STEP(2, t0 - 1);
            L0_STEP(1, t0 - 2);
            L0_STEP(0, t0 - 3);
        } else {
            const int t0 = 4 * chk;
            L0_STEP(0, t0);
            L0_STEP(1, t0 + 1);
            L0_STEP(2, t0 + 2);
            L0_STEP(3, t0 + 3);
        }
    }
}

// ---------------- K2: LSTM layer 1 + MFMA-fc1 + fc2 ----------------
// (R6/R7 version, kept: barrier-free; wave-private hst slab + a2; B-frags from
// L2-hot w2g; per-dir partial acc summed in epilogue; packed-fp32 gates.)
__global__ __launch_bounds__(256, 4) void l1fc_kernel(
    const unsigned* __restrict__ hin,   // [T][2][B] packed bf16 pairs
    const float* __restrict__ wih_f, const float* __restrict__ whh_f,
    const float* __restrict__ bih_f, const float* __restrict__ bhh_f,
    const float* __restrict__ wih_r, const float* __restrict__ whh_r,
    const float* __restrict__ bih_r, const float* __restrict__ bhh_r,
    const unsigned* __restrict__ w2g,   // [10][2][64][32] bf16 = [10][2][64][16] dw
    const float* __restrict__ fc1_b,
    const float* __restrict__ fc2_w,    // [20][64]
    const float* __restrict__ fc2_b,
    float* __restrict__ out)            // [B][20]
{
    __shared__ unsigned smem[7680];     // 30,720 B: a2 [4][32][20] + hst [4][2][2][10][32]

    const int tid  = threadIdx.x;
    const int wv   = tid >> 6;          // 0..3
    const int lane = tid & 63;
    const int d    = wv >> 1;           // waves 0-1: fwd, 2-3: rev
    const int shalf = wv & 1;
    const int cid  = lane & 1;
    const int sp   = lane >> 1;         // 0..31 sample-in-wave
    const int b0   = blockIdx.x * 64;

    unsigned* a2w  = smem + wv * 640;           // per-wave [32][20] dw (cols 10..15 K-pad)
    unsigned* hstw = smem + 2560 + wv * 1280;   // per-wave [2buf][2p][10][32] dw

    const float* wih = d ? wih_r : wih_f;
    const float* whh = d ? whh_r : whh_f;
    const float* bih = d ? bih_r : bih_f;
    const float* bhh = d ? bhh_r : bhh_f;

    float2v wi2[2][4], whA2[2], whB2[2], bias2[2];
#pragma unroll
    for (int p = 0; p < 2; ++p) {
        const int k0 = cid + 4 * p, k1 = cid + 4 * p + 2;
#pragma unroll
        for (int m = 0; m < 4; ++m)
            wi2[p][m] = (float2v){wih[k0 * 4 + m], wih[k1 * 4 + m]};
        whA2[p]  = (float2v){whh[k0 * 2 + cid], whh[k1 * 2 + cid]};
        whB2[p]  = (float2v){whh[k0 * 2 + (cid ^ 1)], whh[k1 * 2 + (cid ^ 1)]};
        bias2[p] = (float2v){bih[k0] + bhh[k0], bih[k1] + bhh[k1]};
    }

    float4v acc[2][4];                  // [mt][nt] partial C for this wave's dir
#pragma unroll
    for (int mt = 0; mt < 2; ++mt)
#pragma unroll
        for (int nt = 0; nt < 4; ++nt) acc[mt][nt] = (float4v){0.f, 0.f, 0.f, 0.f};

    for (int i = lane; i < 640; i += 64) a2w[i] = 0u;   // zero incl. K-pad cols (wave-private)

    // wave-private h slab: 20 rows R=[p][j] of 32 dw; LDS dst = uniform base + lane
    auto stage_h = [&](int w, int pb) {
        unsigned* dst = hstw + pb * 640;
        const int col = lane & 31;
        const int Rb  = lane >> 5;         // 0/1
#pragma unroll
        for (int i = 0; i < 10; ++i) {
            const int R = Rb + 2 * i;      // 0..19
            const int p = (R >= 10) ? 1 : 0;
            const int j = R - 10 * p;
            const int t = d ? (99 - (10 * w + j)) : (10 * w + j);
            async_copy_dw(hin + ((size_t)t * 2 + p) * Bn + b0 + shalf * 32 + col,
                          dst + R * 32 + col);
        }
    };

    stage_h(0, 0);

    float hs = 0.f, ho = 0.f, cc = 0.f;
    const int q = lane >> 4, l16 = lane & 15;

#pragma unroll 1
    for (int w = 0; w < 10; ++w) {
        __builtin_amdgcn_s_waitcnt(0x0F70);   // this window's h slab landed
        __builtin_amdgcn_sched_barrier(0);

        // B-fragments for this window/dir straight from global (L2/L3-hot, 1KB/wave)
        short8 bv[4];
#pragma unroll
        for (int nt = 0; nt < 4; ++nt)
            bv[nt] = *(const short8*)&w2g[w * 2048 + d * 1024 + (nt * 16 + l16) * 16 + q * 4];

        if (w < 9) stage_h(w + 1, (w + 1) & 1);
        __builtin_amdgcn_sched_barrier(0);

        // ---- 10 LSTM steps (wave-private LDS only) ----
        const unsigned* hb = hstw + (w & 1) * 640;
#pragma unroll 2
        for (int j = 0; j < 10; ++j) {
            const unsigned uF = hb[j * 32 + sp];
            const unsigned uR = hb[320 + j * 32 + sp];
            const float a0 = bf_lo(uF), a1 = bf_hi(uF);
            const float a2v = bf_lo(uR), a3 = bf_hi(uR);

            float2v g0 = bias2[0], g1 = bias2[1];
            g0 = pk_fma(wi2[0][0], pk2(a0), g0);  g1 = pk_fma(wi2[1][0], pk2(a0), g1);
            g0 = pk_fma(wi2[0][1], pk2(a1), g0);  g1 = pk_fma(wi2[1][1], pk2(a1), g1);
            g0 = pk_fma(wi2[0][2], pk2(a2v), g0); g1 = pk_fma(wi2[1][2], pk2(a2v), g1);
            g0 = pk_fma(wi2[0][3], pk2(a3), g0);  g1 = pk_fma(wi2[1][3], pk2(a3), g1);
            g0 = pk_fma(whA2[0], pk2(hs), pk_fma(whB2[0], pk2(ho), g0));
            g1 = pk_fma(whA2[1], pk2(hs), pk_fma(whB2[1], pk2(ho), g1));

            const float iv = sig_f(g0.x);
            const float fv = sig_f(g0.y);
            const float qv = tanh_f(g1.x);
            const float ov = sig_f(g1.y);
            cc = fmaf(fv, cc, iv * qv);
            hs = ov * tanh_f(cc);
            ho = dpp_xor1(hs);

            if (cid == 0)
                a2w[sp * 20 + j] = bf16rne(fmaxf(hs, 0.f)) | (bf16rne(fmaxf(ho, 0.f)) << 16);
        }
        asm volatile("s_waitcnt lgkmcnt(0)");   // a2 writes visible to own wave's lanes
        __builtin_amdgcn_sched_barrier(0);

        // ---- MFMA: partial C[32x64] (this dir) += A2·W2^T, K=32; 2 m-tiles x 4 n-tiles
        {
            short8 av0 = *(const short8*)&a2w[l16 * 20 + q * 4];
            short8 av1 = *(const short8*)&a2w[(16 + l16) * 20 + q * 4];
#pragma unroll
            for (int nt = 0; nt < 4; ++nt) {
                acc[0][nt] = __builtin_amdgcn_mfma_f32_16x16x32_bf16(av0, bv[nt], acc[0][nt], 0, 0, 0);
                acc[1][nt] = __builtin_amdgcn_mfma_f32_16x16x32_bf16(av1, bv[nt], acc[1][nt], 0, 0, 0);
            }
        }
    }

    // ---- epilogue: sum dir partials in LDS, +bias, relu, fc2, out ----
    __syncthreads();                       // all waves done with hst/a2; safe to reuse smem
    float* eb = (float*)smem;              // [64][65]
    if (d == 0) {
#pragma unroll
        for (int mt = 0; mt < 2; ++mt)
#pragma unroll
            for (int nt = 0; nt < 4; ++nt)
#pragma unroll
                for (int r = 0; r < 4; ++r)
                    eb[(shalf * 32 + mt * 16 + q * 4 + r) * 65 + nt * 16 + l16] = acc[mt][nt][r];
    }
    __syncthreads();
    if (d == 1) {
#pragma unroll
        for (int mt = 0; mt < 2; ++mt)
#pragma unroll
            for (int nt = 0; nt < 4; ++nt)
#pragma unroll
                for (int r = 0; r < 4; ++r)
                    eb[(shalf * 32 + mt * 16 + q * 4 + r) * 65 + nt * 16 + l16] += acc[mt][nt][r];
    }
    __syncthreads();

    const float* ebr = (const float*)smem;
    const int sm2 = tid & 63;
    const int og  = (tid >> 6) * 5;        // 4 groups x 5 outputs
    float z[64];
#pragma unroll
    for (int k = 0; k < 64; ++k) z[k] = fmaxf(ebr[sm2 * 65 + k] + fc1_b[k], 0.f);
    float y[5];
#pragma unroll
    for (int o = 0; o < 5; ++o) {
        float r2 = fc2_b[og + o];
#pragma unroll
        for (int k = 0; k < 64; ++k) r2 = fmaf(fc2_w[(og + o) * 64 + k], z[k], r2);
        y[o] = r2;
    }
    __syncthreads();
    float* ebw = (float*)smem;
#pragma unroll
    for (int o = 0; o < 5; ++o) ebw[sm2 * 20 + og + o] = y[o];
    __syncthreads();
    for (int f = tid; f < 1280; f += 256)
        out[(size_t)blockIdx.x * 1280 + f] = ebw[f];
}

extern "C" void kernel_launch(void* const* d_in, const int* in_sizes, int n_in,
                              void* d_out, int out_size, void* d_ws, size_t ws_size,
                              hipStream_t stream) {
    const float* x = (const float*)d_in[0];
    const float* w_ih_l0  = (const float*)d_in[1];
    const float* w_hh_l0  = (const float*)d_in[2];
    const float* b_ih_l0  = (const float*)d_in[3];
    const float* b_hh_l0  = (const float*)d_in[4];
    const float* w_ih_l0r = (const float*)d_in[5];
    const float* w_hh_l0r = (const float*)d_in[6];
    const float* b_ih_l0r = (const float*)d_in[7];
    const float* b_hh_l0r = (const float*)d_in[8];
    const float* w_ih_l1  = (const float*)d_in[9];
    const float* w_hh_l1  = (const float*)d_in[10];
    const float* b_ih_l1  = (const float*)d_in[11];
    const float* b_hh_l1  = (const float*)d_in[12];
    const float* w_ih_l1r = (const float*)d_in[13];
    const float* w_hh_l1r = (const float*)d_in[14];
    const float* b_ih_l1r = (const float*)d_in[15];
    const float* b_hh_l1r = (const float*)d_in[16];
    const float* fc1_w = (const float*)d_in[17];
    const float* fc1_b = (const float*)d_in[18];
    const float* fc2_w = (const float*)d_in[19];
    const float* fc2_b = (const float*)d_in[20];

    unsigned* h1u = (unsigned*)d_ws;                                // [100][2][65536] u32 = 52,428,800 B
    unsigned short* w2g = (unsigned short*)((char*)d_ws + (size_t)Tn * 2 * Bn * 4);  // 81,920 B

    w2prep_kernel<<<160, 256, 0, stream>>>(fc1_w, w2g);
    l0_kernel<<<1024, 256, 0, stream>>>(x,
        w_ih_l0, w_hh_l0, b_ih_l0, b_hh_l0,
        w_ih_l0r, w_hh_l0r, b_ih_l0r, b_hh_l0r, h1u);
    l1fc_kernel<<<1024, 256, 0, stream>>>(h1u,
        w_ih_l1, w_hh_l1, b_ih_l1, b_hh_l1,
        w_ih_l1r, w_hh_l1r, b_ih_l1r, b_hh_l1r,
        (const unsigned*)w2g, fc1_b, fc2_w, fc2_b, (float*)d_out);
}